// Round 10
// baseline (66.865 us; speedup 1.0000x reference)
//
#include <hip/hip_runtime.h>

// ConvSSM scan, spatial domain, step-doubled, 512-thread scan, packed-f32 FMA.
//   h_t = A (*) h_{t-1} + u_t,  u_t = B (*) xpad_t,  (*) = circular conv on 64x64.
// H_m = h_{2m+1}:
//   H_m  = A2 (*) H_{m-1} + G_m,  A2 = A(*)A (5x5),  G_m = A(*)u_{2m} + u_{2m+1}
//   h_2m = A  (*) H_{m-1} + u_{2m}   (even emit, crop region only)
// Pass 1 (2112 blocks, vectorized, magic-div): U_m (32x32), G_m (36x36) -> d_ws,
//   padded with one all-zero tile at m=MH so the scan prefetch needs no branch.
// Pass 2 (64 blocks x 512 thr): 32-step scan, h in LDS dbuf, 2x4 px/thread,
//   6x8 window (lo half via DPP row_ror:1), conv as float2 v_pk_fma_f32.

constexpr int T_STEPS = 64;
constexpr int B_DIM   = 2;
constexpr int C_DIM   = 32;
constexpr int HW      = 32;
constexpr int N       = 64;
constexpr int NIMG    = B_DIM * C_DIM;   // 64
constexpr int MH      = T_STEPS / 2;     // 32 scan steps
constexpr int MT      = MH + 1;          // stored tiles per image (pad tile = 0)
constexpr int HSTR    = 68;              // LDS row stride (floats)
constexpr int GSZ     = 36 * 36;         // 1296 floats
constexpr int USZ     = HW * HW;         // 1024 floats

typedef float f2 __attribute__((ext_vector_type(2)));

__device__ __forceinline__ f2 fma2(f2 a, f2 b, f2 c) {
    return __builtin_elementwise_fma(a, b, c);   // -> v_pk_fma_f32 on gfx950
}

__device__ __forceinline__ float rfl(float v) {
    return __int_as_float(__builtin_amdgcn_readfirstlane(__float_as_int(v)));
}

// dst lane g receives src lane (g-1)&15 within each 16-lane DPP row (row_ror:1)
__device__ __forceinline__ float ror1(float x) {
    return __int_as_float(__builtin_amdgcn_update_dpp(
        0, __float_as_int(x), 0x121, 0xF, 0xF, false));
}

// ---------------- Pass 1: U_m (32x32), G_m (36x36) per (m, bc) ---------------
__global__ __launch_bounds__(256)
void convssm_pass1e(const float* __restrict__ x_seq,  // (T,B,C,32,32)
                    const float* __restrict__ A_k,    // (C,3,3)
                    const float* __restrict__ B_k,    // (C,3,3)
                    float* __restrict__ U,            // (NIMG*MT, 32, 32) idx bc*MT+m
                    float* __restrict__ G)            // (NIMG*MT, 36, 36)
{
    __shared__ __align__(16) float xe[32][36];
    __shared__ __align__(16) float xo[32][36];
    __shared__ __align__(16) float ue[34][36];

    const int blk = blockIdx.x;           // m*64 + bc, m in [0, MH]
    const int m   = blk >> 6;
    const int bc  = blk & 63;
    const int c   = bc & 31;
    const int tid = threadIdx.x;

    float* Ug = U + (size_t)(bc * MT + m) * USZ;
    float* Gg = G + (size_t)(bc * MT + m) * GSZ;

    if (m == MH) {   // pad tile: all zeros (ws is poisoned -> must write)
        const float4 z4 = make_float4(0.f, 0.f, 0.f, 0.f);
        *(float4*)(Ug + tid * 4) = z4;
        for (int i4 = tid; i4 < 324; i4 += 256)
            *(float4*)(Gg + i4 * 4) = z4;
        return;
    }

    float a[9], bw[9];
#pragma unroll
    for (int i = 0; i < 9; ++i) { a[i] = A_k[c * 9 + i]; bw[i] = B_k[c * 9 + i]; }

    const float4* xE = (const float4*)(x_seq + ((size_t)(2 * m)     * NIMG + bc) * (HW * HW));
    const float4* xO = (const float4*)(x_seq + ((size_t)(2 * m + 1) * NIMG + bc) * (HW * HW));
    {
        const int y  = tid >> 3;          // 0..31
        const int x4 = (tid & 7) * 4;     // 0,4,...,28
        *(float4*)&xe[y][x4] = xE[tid];
        *(float4*)&xo[y][x4] = xO[tid];
    }
    __syncthreads();

    // ue = B (*) xpad_{2m} over rows 0..33, cols 0..35 (cols 34,35 -> 0)
    for (int i4 = tid; i4 < 306; i4 += 256) {       // 34 rows x 9 words
        const int y  = (i4 * 57) >> 9;              // i4 / 9 (valid i4 < 324)
        const int x0 = (i4 - y * 9) * 4;
        float r[4];
#pragma unroll
        for (int j = 0; j < 4; ++j) {
            const int xx = x0 + j;
            float v = 0.0f;
#pragma unroll
            for (int ky = 0; ky < 3; ++ky) {
                const int yy = y - ky;
                if (yy < 0 || yy >= 32) continue;
#pragma unroll
                for (int kx = 0; kx < 3; ++kx) {
                    const int xs = xx - kx;
                    if (xs < 0 || xs >= 32) continue;
                    v += bw[ky * 3 + kx] * xe[yy][xs];
                }
            }
            r[j] = v;
        }
        *(float4*)&ue[y][x0] = make_float4(r[0], r[1], r[2], r[3]);
        if (y < 32 && x0 < 32)
            *(float4*)(Ug + y * HW + x0) = make_float4(r[0], r[1], r[2], r[3]);
    }
    __syncthreads();

    // G_m = B (*) xpad_{2m+1} + A (*) ue : support 36x36
    for (int i4 = tid; i4 < 324; i4 += 256) {       // 36 rows x 9 words
        const int y  = (i4 * 57) >> 9;
        const int x0 = (i4 - y * 9) * 4;
        float r[4];
#pragma unroll
        for (int j = 0; j < 4; ++j) {
            const int xx = x0 + j;
            float v = 0.0f;
#pragma unroll
            for (int ky = 0; ky < 3; ++ky) {
#pragma unroll
                for (int kx = 0; kx < 3; ++kx) {
                    const int yy = y - ky, xs = xx - kx;
                    if (yy >= 0 && yy < 32 && xs >= 0 && xs < 32)
                        v += bw[ky * 3 + kx] * xo[yy][xs];
                    if (yy >= 0 && yy < 34 && xs >= 0 && xs < 34)
                        v += a[ky * 3 + kx] * ue[yy][xs];
                }
            }
            r[j] = v;
        }
        *(float4*)(Gg + y * 36 + x0) = make_float4(r[0], r[1], r[2], r[3]);
    }
}

// ---------------- Pass 2: 32-step scan, 512 threads, pk-fma ------------------
__global__ __launch_bounds__(512, 2)
void convssm_scan7(const float* __restrict__ U,
                   const float* __restrict__ G,
                   const float* __restrict__ A_k,
                   float* __restrict__ out)          // (T,B,C,32,32)
{
    __shared__ __align__(16) float hbuf[2][N * HSTR];

    const int bc  = blockIdx.x;          // 0..63
    const int c   = bc & 31;
    const int tid = threadIdx.x;
    const int g   = tid & 15;            // col group: cols 4g..4g+3
    const int s   = tid >> 4;            // 0..31: rows 2s, 2s+1
    const int y0  = s * 2;
    const int xc  = g * 4;

    // A, A2 (block-uniform; rfl -> scalar regs)
    float afs[9];
#pragma unroll
    for (int i = 0; i < 9; ++i) afs[i] = A_k[c * 9 + i];

    float a2s[25];
#pragma unroll
    for (int p = 0; p < 5; ++p) {
#pragma unroll
        for (int q = 0; q < 5; ++q) {
            float v = 0.0f;
#pragma unroll
            for (int ky = 0; ky < 3; ++ky) {
                const int py = p - ky;
                if (py < 0 || py > 2) continue;
#pragma unroll
                for (int kx = 0; kx < 3; ++kx) {
                    const int qx = q - kx;
                    if (qx < 0 || qx > 2) continue;
                    v += afs[ky * 3 + kx] * afs[py * 3 + qx];
                }
            }
            a2s[p * 5 + q] = v;
        }
    }
#pragma unroll
    for (int i = 0; i < 25; ++i) a2s[i] = rfl(a2s[i]);
#pragma unroll
    for (int i = 0; i < 9; ++i)  afs[i] = rfl(afs[i]);

    // duplicated float2 coefficients for pk-fma
    f2 a2d[25], afd[9];
#pragma unroll
    for (int i = 0; i < 25; ++i) a2d[i] = (f2){a2s[i], a2s[i]};
#pragma unroll
    for (int i = 0; i < 9; ++i)  afd[i] = (f2){afs[i], afs[i]};

    for (int i = tid; i < N * HSTR; i += 512) hbuf[0][i] = 0.0f;

    const bool gok   = (y0 <= 34) && (xc <= 32);
    const bool cropw = (y0 < HW);
    const bool crop  = cropw && (xc < HW);

    const float* Ub = U + (size_t)bc * MT * USZ + y0 * HW + xc;
    const float* Gb = G + (size_t)bc * MT * GSZ + y0 * 36 + xc;

    const float4 z4 = make_float4(0.f, 0.f, 0.f, 0.f);
    float4 gc0 = z4, gc1 = z4, uc0 = z4, uc1 = z4;
    if (gok) {
        gc0 = *(const float4*)(Gb);
        gc1 = *(const float4*)(Gb + 36);
    }
    if (crop) {
        uc0 = *(const float4*)(Ub);
        uc1 = *(const float4*)(Ub + HW);
    }

    float* hold = &hbuf[0][0];
    float* hnew = &hbuf[1][0];
    float* ob   = out + (size_t)bc * (HW * HW);
    const size_t tstr = (size_t)NIMG * (HW * HW);  // 65536

    float4 acc0 = z4, acc1 = z4;   // own rows y0,y0+1 cols xc..xc+3 of h_old

    __syncthreads();

    for (int m = 0; m < MH; ++m) {
        // prefetch next step's G / U (pad tile at m=MH -> no branch)
        float4 gn0 = z4, gn1 = z4, un0 = z4, un1 = z4;
        if (gok) {
            const float* p = Gb + (size_t)(m + 1) * GSZ;
            gn0 = *(const float4*)(p);
            gn1 = *(const float4*)(p + 36);
        }
        if (crop) {
            const float* p = Ub + (size_t)(m + 1) * USZ;
            un0 = *(const float4*)(p);
            un1 = *(const float4*)(p + HW);
        }

        // 6x8 window rows y0-4..y0+1: hi from LDS (4 rows) + acc regs (2 rows);
        // lo (cols xc-4..xc-1) via DPP; sh = odd-offset pairs for pk-fma.
        // Pair layout per row i: w2[i][k] = cols (2k, 2k+1) of window idx 0..7,
        // window idx d = col (xc-4+d) mod 64. sh[i][r] = (idx 2r+1, idx 2r+2).
        f2 w2[6][4], sh[6][3];
#pragma unroll
        for (int i = 0; i < 6; ++i) {
            float4 h4;
            if (i < 4) {
                const int rr = (y0 + 60 + i) & 63;
                h4 = *(const float4*)(hold + rr * HSTR + xc);
            } else {
                h4 = (i == 4) ? acc0 : acc1;
            }
            w2[i][2] = (f2){h4.x, h4.y};
            w2[i][3] = (f2){h4.z, h4.w};
            w2[i][0] = (f2){ror1(h4.x), ror1(h4.y)};
            w2[i][1] = (f2){ror1(h4.z), ror1(h4.w)};
            sh[i][0] = (f2){w2[i][0].y, w2[i][1].x};
            sh[i][1] = (f2){w2[i][1].y, w2[i][2].x};
            sh[i][2] = (f2){w2[i][2].y, w2[i][3].x};
        }

        // H_new = A2 (*) H_old + G   (rows r=0,1; o[j] pairs (0,1),(2,3))
        f2 o01 = (f2){gc0.x, gc0.y}, o23 = (f2){gc0.z, gc0.w};
        f2 p01 = (f2){gc1.x, gc1.y}, p23 = (f2){gc1.z, gc1.w};
#pragma unroll
        for (int p = 0; p < 5; ++p) {
            const int i  = 4 - p;      // r=0
            const int i2 = 5 - p;      // r=1
            const f2 c0 = a2d[p * 5 + 0], c1 = a2d[p * 5 + 1], c2 = a2d[p * 5 + 2],
                     c3 = a2d[p * 5 + 3], c4 = a2d[p * 5 + 4];
            o01 = fma2(c0, w2[i][2], o01);
            o01 = fma2(c1, sh[i][1], o01);
            o01 = fma2(c2, w2[i][1], o01);
            o01 = fma2(c3, sh[i][0], o01);
            o01 = fma2(c4, w2[i][0], o01);
            o23 = fma2(c0, w2[i][3], o23);
            o23 = fma2(c1, sh[i][2], o23);
            o23 = fma2(c2, w2[i][2], o23);
            o23 = fma2(c3, sh[i][1], o23);
            o23 = fma2(c4, w2[i][1], o23);
            p01 = fma2(c0, w2[i2][2], p01);
            p01 = fma2(c1, sh[i2][1], p01);
            p01 = fma2(c2, w2[i2][1], p01);
            p01 = fma2(c3, sh[i2][0], p01);
            p01 = fma2(c4, w2[i2][0], p01);
            p23 = fma2(c0, w2[i2][3], p23);
            p23 = fma2(c1, sh[i2][2], p23);
            p23 = fma2(c2, w2[i2][2], p23);
            p23 = fma2(c3, sh[i2][1], p23);
            p23 = fma2(c4, w2[i2][1], p23);
        }
        const float4 accn0 = make_float4(o01.x, o01.y, o23.x, o23.y);
        const float4 accn1 = make_float4(p01.x, p01.y, p23.x, p23.y);

        // even emit: h_{2m} = A (*) H_old + u_{2m}
        if (cropw) {
            f2 e01 = (f2){uc0.x, uc0.y}, e23 = (f2){uc0.z, uc0.w};
            f2 f01 = (f2){uc1.x, uc1.y}, f23 = (f2){uc1.z, uc1.w};
#pragma unroll
            for (int ky = 0; ky < 3; ++ky) {
                const int i  = 4 - ky;
                const int i2 = 5 - ky;
                const f2 c0 = afd[ky * 3 + 0], c1 = afd[ky * 3 + 1], c2 = afd[ky * 3 + 2];
                e01 = fma2(c0, w2[i][2], e01);
                e01 = fma2(c1, sh[i][1], e01);
                e01 = fma2(c2, w2[i][1], e01);
                e23 = fma2(c0, w2[i][3], e23);
                e23 = fma2(c1, sh[i][2], e23);
                e23 = fma2(c2, w2[i][2], e23);
                f01 = fma2(c0, w2[i2][2], f01);
                f01 = fma2(c1, sh[i2][1], f01);
                f01 = fma2(c2, w2[i2][1], f01);
                f23 = fma2(c0, w2[i2][3], f23);
                f23 = fma2(c1, sh[i2][2], f23);
                f23 = fma2(c2, w2[i2][2], f23);
            }
            if (crop) {
                float* oe = ob + (size_t)(2 * m) * tstr;
                float* oo = oe + tstr;
                *(float4*)(oe + y0 * HW + xc)       = make_float4(e01.x, e01.y, e23.x, e23.y);
                *(float4*)(oe + (y0 + 1) * HW + xc) = make_float4(f01.x, f01.y, f23.x, f23.y);
                *(float4*)(oo + y0 * HW + xc)       = accn0;
                *(float4*)(oo + (y0 + 1) * HW + xc) = accn1;
            }
        }

        *(float4*)(hnew + y0 * HSTR + xc)       = accn0;
        *(float4*)(hnew + (y0 + 1) * HSTR + xc) = accn1;

        __syncthreads();   // hnew complete; all reads of hold done

        float* tmp = hold; hold = hnew; hnew = tmp;
        acc0 = accn0; acc1 = accn1;
        gc0 = gn0; gc1 = gn1;
        uc0 = un0; uc1 = un1;
    }
}

// ---------------- Fallback (round-1 fused, known-correct) --------------------
__global__ __launch_bounds__(256)
void convssm_scan_fused(const float* __restrict__ x_seq,
                        const float* __restrict__ A_k,
                        const float* __restrict__ B_k,
                        float* __restrict__ out)
{
    __shared__ float h0[N][N];
    __shared__ float h1[N][N];
    __shared__ float xs[N][N];

    const int bc = blockIdx.x;
    const int b  = bc >> 5;
    const int c  = bc & 31;
    const int tid = threadIdx.x;
    const int x   = tid & 63;
    const int y0  = (tid >> 6) << 4;

    float a[9], bw[9];
#pragma unroll
    for (int i = 0; i < 9; ++i) { a[i] = A_k[c*9+i]; bw[i] = B_k[c*9+i]; }
#pragma unroll
    for (int r = 0; r < 16; ++r) { h0[y0+r][x] = 0.f; xs[y0+r][x] = 0.f; }

    float (*hold)[N] = h0;
    float (*hnew)[N] = h1;
    const int xm1 = (x + 63) & 63, xm2 = (x + 62) & 63;
    const size_t img = (size_t)HW*HW, tstr = (size_t)NIMG*img;
    const float* xbase = x_seq + ((size_t)b*C_DIM + c)*img;
    float* obase = out + ((size_t)b*C_DIM + c)*img;
    const bool loader = (x < HW);

    for (int t = 0; t < T_STEPS; ++t) {
        if (loader) {
#pragma unroll
            for (int r = 0; r < 16; ++r) {
                int yy = y0 + r;
                if (yy < HW) xs[yy][x] = xbase[(size_t)t*tstr + yy*HW + x];
            }
        }
        __syncthreads();
        const int ym1 = (y0 + N - 1) & 63, ym2 = (y0 + N - 2) & 63;
        float hr1c0 = hold[ym1][x], hr1c1 = hold[ym1][xm1], hr1c2 = hold[ym1][xm2];
        float hr2c0 = hold[ym2][x], hr2c1 = hold[ym2][xm1], hr2c2 = hold[ym2][xm2];
        float sr1c0 = xs[ym1][x], sr1c1 = xs[ym1][xm1], sr1c2 = xs[ym1][xm2];
        float sr2c0 = xs[ym2][x], sr2c1 = xs[ym2][xm1], sr2c2 = xs[ym2][xm2];
#pragma unroll
        for (int r = 0; r < 16; ++r) {
            const int yy = y0 + r;
            float hr0c0 = hold[yy][x], hr0c1 = hold[yy][xm1], hr0c2 = hold[yy][xm2];
            float sr0c0 = xs[yy][x], sr0c1 = xs[yy][xm1], sr0c2 = xs[yy][xm2];
            float v = a[0]*hr0c0 + a[1]*hr0c1 + a[2]*hr0c2
                    + a[3]*hr1c0 + a[4]*hr1c1 + a[5]*hr1c2
                    + a[6]*hr2c0 + a[7]*hr2c1 + a[8]*hr2c2
                    + bw[0]*sr0c0 + bw[1]*sr0c1 + bw[2]*sr0c2
                    + bw[3]*sr1c0 + bw[4]*sr1c1 + bw[5]*sr1c2
                    + bw[6]*sr2c0 + bw[7]*sr2c1 + bw[8]*sr2c2;
            hnew[yy][x] = v;
            if (yy < HW && x < HW) obase[(size_t)t*tstr + yy*HW + x] = v;
            hr2c0=hr1c0; hr2c1=hr1c1; hr2c2=hr1c2;
            hr1c0=hr0c0; hr1c1=hr0c1; hr1c2=hr0c2;
            sr2c0=sr1c0; sr2c1=sr1c1; sr2c2=sr1c2;
            sr1c0=sr0c0; sr1c1=sr0c1; sr1c2=sr0c2;
        }
        __syncthreads();
        float (*tmp)[N] = hold; hold = hnew; hnew = tmp;
    }
}

extern "C" void kernel_launch(void* const* d_in, const int* in_sizes, int n_in,
                              void* d_out, int out_size, void* d_ws, size_t ws_size,
                              hipStream_t stream)
{
    const float* x_seq = (const float*)d_in[0];
    const float* A_k   = (const float*)d_in[1];
    const float* B_k   = (const float*)d_in[2];
    float* out = (float*)d_out;

    const size_t needU = (size_t)NIMG * MT * USZ;             // floats
    const size_t needG = (size_t)NIMG * MT * GSZ;
    const size_t need  = (needU + needG) * sizeof(float);     // ~19.6 MB

    if (ws_size >= need) {
        float* U = (float*)d_ws;
        float* G = U + needU;
        convssm_pass1e<<<dim3(MT * NIMG), dim3(256), 0, stream>>>(
            x_seq, A_k, B_k, U, G);
        convssm_scan7<<<dim3(NIMG), dim3(512), 0, stream>>>(
            U, G, A_k, out);
    } else {
        convssm_scan_fused<<<dim3(NIMG), dim3(256), 0, stream>>>(
            x_seq, A_k, B_k, out);
    }
}